// Round 14
// baseline (151.350 us; speedup 1.0000x reference)
//
#include <hip/hip_runtime.h>
#include <hip/hip_bf16.h>
#include <stdint.h>

#define BATCH   65536
#define UNITS   256
#define NCH     16                     // BK=32
#define ROWP    68                     // shorts per column in gate buffer
#define GSZ     (64 * ROWP)            // 4352 shorts per gate (per 64-row phase)
#define SMEM_BYTES 65536               // A dbuf 2*8K + B ring 3*16K; G (34816) reuses

using f32x16 = __attribute__((ext_vector_type(16))) float;
using bf16x8 = __attribute__((ext_vector_type(8))) short;

__device__ __forceinline__ short f2bf(float f) {
  union { float f; unsigned u; } v; v.f = f;
  unsigned r = v.u + 0x7FFFu + ((v.u >> 16) & 1u);   // RNE (prepass only)
  return (short)(r >> 16);
}
__device__ __forceinline__ float bf2f(short s) {
  union { float f; unsigned u; } v; v.u = ((unsigned)(unsigned short)s) << 16;
  return v.f;
}
__device__ __forceinline__ unsigned pk2(float a, float b) {   // v_cvt_pk_bf16_f32
  union { __hip_bfloat162 h; unsigned u; } cv;
  cv.h = __float22bfloat162_rn(make_float2(a, b));
  return cv.u;
}
__device__ __forceinline__ bf16x8 cvt8(float4 a, float4 b) {
  union { unsigned u[4]; bf16x8 v; } r;
  r.u[0] = pk2(a.x, a.y); r.u[1] = pk2(a.z, a.w);
  r.u[2] = pk2(b.x, b.y); r.u[3] = pk2(b.z, b.w);
  return r.v;
}
#define LOG2E 1.4426950408889634f
__device__ __forceinline__ float fast_sigmoid(float x) {
  return __builtin_amdgcn_rcpf(1.f + __builtin_amdgcn_exp2f(x * -LOG2E));
}
__device__ __forceinline__ float fast_tanh(float x) {
  return 2.f * __builtin_amdgcn_rcpf(1.f + __builtin_amdgcn_exp2f(x * (-2.f * LOG2E))) - 1.f;
}

#define BAR() do { asm volatile("s_waitcnt lgkmcnt(0)" ::: "memory"); \
                   __builtin_amdgcn_s_barrier(); } while (0)
#define WAITV(n) asm volatile("s_waitcnt vmcnt(" #n ")" ::: "memory")

__device__ __forceinline__ void gload_lds16(const void* gsrc, void* ldst) {
  __builtin_amdgcn_global_load_lds(
      (const __attribute__((address_space(1))) void*)gsrc,
      (__attribute__((address_space(3))) void*)ldst,
      16, 0, 0);
}

// ---- prepass: W_g fp32 [512][256] -> Wt bf16 tiled [g][nb][kg 64][n 64][k8]
__global__ void cvt_weights(const float* __restrict__ Wf, const float* __restrict__ Wi,
                            const float* __restrict__ Wc, const float* __restrict__ Wo,
                            short* __restrict__ Wt) {
  int idx = blockIdx.x * 256 + threadIdx.x;
  int g   = idx >> 17;
  int k   = (idx >> 8) & 511;
  int col = idx & 255;
  const float* W = (g == 0) ? Wf : (g == 1) ? Wi : (g == 2) ? Wc : Wo;
  float val = W[k * 256 + col];
  int nb = col >> 6, n = col & 63;
  int kg = k >> 3, k8 = k & 7;
  int out = (((g * 4 + nb) * 64 + kg) * 64 + n) * 8 + k8;
  Wt[out] = f2bf(val);
}

// ---- fused LSTM cell: BM=128, 8 waves = (gate, m-half). B staged per chunk
// into a 3-slot LDS ring (shared across m-halves, race-free), counted vmcnt.
// 2048 blocks of 512 thr; 2 blocks/CU; per-wave core identical to R13.
__global__ __launch_bounds__(512, 4) void lstm_fused(
    const float* __restrict__ x, const float* __restrict__ hprev,
    const float* __restrict__ cprev, const short* __restrict__ Wt,
    const float* __restrict__ bfp, const float* __restrict__ bip,
    const float* __restrict__ bcp, const float* __restrict__ bop,
    float* __restrict__ hout, float* __restrict__ cout)
{
  extern __shared__ __align__(16) char smem[];
  const int tid  = threadIdx.x;
  const int gg   = (tid >> 6) & 3;     // gate
  const int mh   = tid >> 8;           // m-half (0/1)
  const int lane = tid & 63;
  const int la   = lane & 31;
  const int hh   = lane >> 5;

  int bid = blockIdx.x;
  int wg  = (bid & 7) * 256 + (bid >> 3);      // XCD-bijective (2048 = 8*256)
  const int m0 = (wg >> 2) * 128;
  const int nb = wg & 3;
  const int n0 = nb * 64;

  const short* WtG = Wt + ((size_t)(gg * 4 + nb)) * 32768;

  f32x16 acc[2][2] = {};
  float4 vA[2][2];

  const int arow = tid >> 2;           // 0..127
  const int q    = tid & 3;            // kg within chunk

  char* Abase = smem;                  // [2][8192]: [kg4][row128][16B]
  char* Bbase = smem + 16384;          // [3][16384]: [gate4][kg4][n64][16B]

  auto ldA = [&](int c) {
    const float* base = (c < 8) ? x : hprev;
    const float* rowp = base + (size_t)(m0 + arow) * 256 + (c & 7) * 32 + q * 8;
    vA[c & 1][0] = *(const float4*)(rowp);
    vA[c & 1][1] = *(const float4*)(rowp + 4);
  };
  auto wrA = [&](int c) {
    char* Ab = Abase + (c & 1) * 8192;
    *(bf16x8*)(Ab + q * 2048 + (arow ^ (q << 2)) * 16) = cvt8(vA[c & 1][0], vA[c & 1][1]);
  };
  auto stageB = [&](int c) {           // 4KB/gate, split across m-half wave pair
    char* ldst = Bbase + (c % 3) * 16384 + gg * 4096 + mh * 2048;
    const short* gs = WtG + c * 2048 + mh * 1024 + lane * 8;
    gload_lds16(gs, ldst);
    gload_lds16(gs + 512, ldst + 1024);
  };
  auto compute = [&](int c) {
    const char* Ab = Abase + (c & 1) * 8192;
    const char* Bl = Bbase + (c % 3) * 16384 + gg * 4096;
#pragma unroll
    for (int ks = 0; ks < 2; ++ks) {
      const int kg = 2 * ks + hh;
      const int ao = kg * 2048 + (((mh * 64 + la) ^ (kg << 2)) * 16);
      bf16x8 a0 = *(const bf16x8*)(Ab + ao);
      bf16x8 a1 = *(const bf16x8*)(Ab + ao + 512);       // rows +32
      bf16x8 b0 = *(const bf16x8*)(Bl + kg * 1024 + la * 16);
      bf16x8 b1 = *(const bf16x8*)(Bl + kg * 1024 + la * 16 + 512);
      acc[0][0] = __builtin_amdgcn_mfma_f32_32x32x16_bf16(a0, b0, acc[0][0], 0, 0, 0);
      acc[0][1] = __builtin_amdgcn_mfma_f32_32x32x16_bf16(a0, b1, acc[0][1], 0, 0, 0);
      acc[1][0] = __builtin_amdgcn_mfma_f32_32x32x16_bf16(a1, b0, acc[1][0], 0, 0, 0);
      acc[1][1] = __builtin_amdgcn_mfma_f32_32x32x16_bf16(a1, b1, acc[1][1], 0, 0, 0);
    }
  };

  // ---- prologue: per-wave VMEM FIFO = A0(2), B0(2), A1(2), B1(2) ----
  ldA(0); stageB(0); ldA(1); stageB(1);
  wrA(0);                              // auto-vmcnt retires A0 only

  // ---- K loop: 1 barrier/chunk; WAITV(4) retires exactly B(c) ----
#pragma unroll
  for (int c = 0; c < NCH; ++c) {
    if (c == NCH - 1) { WAITV(0); } else { WAITV(4); }
    BAR();                             // A(c)+B(c) ready for all waves
    if (c + 1 < NCH) wrA(c + 1);       // writes slot (c+1)&1, disjoint
    compute(c);
    __builtin_amdgcn_sched_barrier(0);
    if (c + 2 < NCH) { ldA(c + 2); stageB(c + 2); }   // B slot (c+2)%3: free
  }

  // ---- epilogue: two 64-row phases, G reuses LDS ----
  const int ccol = tid & 63;
  const int rseg = (tid >> 6) & 7;     // 8 segs x 8 rows = 64 rows per phase
  float cp[16];
#pragma unroll
  for (int ph = 0; ph < 2; ++ph) {
    const size_t gb = (size_t)(m0 + ph * 64 + rseg * 8) * 256 + n0 + ccol;
#pragma unroll
    for (int j = 0; j < 8; ++j) cp[ph * 8 + j] = cprev[gb + (size_t)j * 256];
  }

  const float* bptr = (gg == 0) ? bfp : (gg == 1) ? bip : (gg == 2) ? bcp : bop;
  const float bias0 = bptr[n0 + la];
  const float bias1 = bptr[n0 + 32 + la];
  short* G = (short*)smem;

  auto writeG = [&]() {
#pragma unroll
    for (int mi = 0; mi < 2; ++mi)
#pragma unroll
      for (int ni = 0; ni < 2; ++ni) {
        const float bias = ni ? bias1 : bias0;
        const int   col  = la + ni * 32;
#pragma unroll
        for (int rq = 0; rq < 4; ++rq) {
          const int row0 = rq * 8 + 4 * hh + mi * 32;   // within 64-row half
          float t[4];
#pragma unroll
          for (int e = 0; e < 4; ++e) {
            float vv = acc[mi][ni][rq * 4 + e] + bias;
            t[e] = (gg == 2) ? fast_tanh(vv) : fast_sigmoid(vv);
          }
          uint2 u; u.x = pk2(t[0], t[1]); u.y = pk2(t[2], t[3]);
          *(uint2*)(G + gg * GSZ + col * ROWP + row0) = u;
        }
      }
  };
  auto combine = [&](int ph) {
    const short* Gp = G + ccol * ROWP + rseg * 8;
    bf16x8 gf[4];
#pragma unroll
    for (int t = 0; t < 4; ++t) gf[t] = *(const bf16x8*)(Gp + t * GSZ);
    const size_t gb = (size_t)(m0 + ph * 64 + rseg * 8) * 256 + n0 + ccol;
#pragma unroll
    for (int j = 0; j < 8; ++j) {
      float fg = bf2f(gf[0][j]);
      float ig = bf2f(gf[1][j]);
      float cg = bf2f(gf[2][j]);
      float og = bf2f(gf[3][j]);
      float cnew = fg * cp[ph * 8 + j] + ig * cg;
      float hnew = og * fast_tanh(cnew);
      hout[gb + (size_t)j * 256] = hnew;
      cout[gb + (size_t)j * 256] = cnew;
    }
  };

  BAR();                               // K-loop LDS traffic drained; reuse as G
  if (mh == 0) writeG();
  BAR();
  combine(0);
  BAR();
  if (mh == 1) writeG();
  BAR();
  combine(1);
}

extern "C" void kernel_launch(void* const* d_in, const int* in_sizes, int n_in,
                              void* d_out, int out_size, void* d_ws, size_t ws_size,
                              hipStream_t stream) {
  const float* x     = (const float*)d_in[0];
  const float* hprev = (const float*)d_in[1];
  const float* cprev = (const float*)d_in[2];
  const float* Wf    = (const float*)d_in[3];
  const float* Wi    = (const float*)d_in[4];
  const float* Wc    = (const float*)d_in[5];
  const float* Wo    = (const float*)d_in[6];
  const float* bfp   = (const float*)d_in[7];
  const float* bip   = (const float*)d_in[8];
  const float* bcp   = (const float*)d_in[9];
  const float* bop   = (const float*)d_in[10];
  float* out = (float*)d_out;
  short* Wt  = (short*)d_ws;     // 1 MB scratch

  cvt_weights<<<2048, 256, 0, stream>>>(Wf, Wi, Wc, Wo, Wt);

  lstm_fused<<<dim3(2048), dim3(512), SMEM_BYTES, stream>>>(
      x, hprev, cprev, Wt, bfp, bip, bcp, bop,
      out, out + (size_t)BATCH * UNITS);
}

// Round 15
// 137.111 us; speedup vs baseline: 1.1038x; 1.1038x over previous
//
#include <hip/hip_runtime.h>
#include <hip/hip_bf16.h>
#include <stdint.h>

#define BATCH   65536
#define UNITS   256
#define NCH     16                     // BK = 32
#define ROWP    72                     // shorts per G column (16B-aligned reads)
#define GSZ     (64 * ROWP)            // per-gate G: 64 cols x 72
#define SMEM_BYTES 65536               // A full-K 64x512 bf16; G (36864) reuses it

using f32x16 = __attribute__((ext_vector_type(16))) float;
using bf16x8 = __attribute__((ext_vector_type(8))) short;

__device__ __forceinline__ short f2bf(float f) {
  union { float f; unsigned u; } v; v.f = f;
  unsigned r = v.u + 0x7FFFu + ((v.u >> 16) & 1u);   // RNE (prepass only)
  return (short)(r >> 16);
}
__device__ __forceinline__ float bf2f(short s) {
  union { float f; unsigned u; } v; v.u = ((unsigned)(unsigned short)s) << 16;
  return v.f;
}
__device__ __forceinline__ unsigned pk2(float a, float b) {   // v_cvt_pk_bf16_f32
  union { __hip_bfloat162 h; unsigned u; } cv;
  cv.h = __float22bfloat162_rn(make_float2(a, b));
  return cv.u;
}
#define LOG2E 1.4426950408889634f
__device__ __forceinline__ float fast_sigmoid(float x) {
  return __builtin_amdgcn_rcpf(1.f + __builtin_amdgcn_exp2f(x * -LOG2E));
}
__device__ __forceinline__ float fast_tanh(float x) {
  return 2.f * __builtin_amdgcn_rcpf(1.f + __builtin_amdgcn_exp2f(x * (-2.f * LOG2E))) - 1.f;
}

#define BAR() do { asm volatile("s_waitcnt lgkmcnt(0)" ::: "memory"); \
                   __builtin_amdgcn_s_barrier(); } while (0)
#define WAITV(n) asm volatile("s_waitcnt vmcnt(" #n ")" ::: "memory")

// ---- prepass: W fp32 [512][256] -> Wt bf16 [g][nt32 8][c 16][ks 2][l 64][8]
// (per 32-col tile: each chunk's B-fragment = contiguous 16B/lane, 2KB/chunk)
__global__ void cvt_weights(const float* __restrict__ Wf, const float* __restrict__ Wi,
                            const float* __restrict__ Wc, const float* __restrict__ Wo,
                            short* __restrict__ Wt) {
  int idx = blockIdx.x * 256 + threadIdx.x;
  int g   = idx >> 17;
  int k   = (idx >> 8) & 511;
  int col = idx & 255;
  const float* W = (g == 0) ? Wf : (g == 1) ? Wi : (g == 2) ? Wc : Wo;
  float val = W[k * 256 + col];
  int nt = col >> 5;
  int c = k >> 5, ks = (k >> 4) & 1, hi = (k >> 3) & 1, e = k & 7;
  int out = ((((g * 8 + nt) * 16 + c) * 2 + ks) * 64 + hi * 32 + (col & 31)) * 8 + e;
  Wt[out] = f2bf(val);
}

// ---- fused LSTM: 8 waves = (4 gates x 2 n-halves), wave tile 64x32 (acc 32 AGPR).
// A full-K in LDS staged ONCE; K-loop has ZERO barriers, ZERO LDS writes;
// B in a 4-deep register ring from L2 (contiguous), counted vmcnt(6).
__global__ __launch_bounds__(512, 4) void lstm_fused(
    const float* __restrict__ x, const float* __restrict__ hprev,
    const float* __restrict__ cprev, const short* __restrict__ Wt,
    const float* __restrict__ bfp, const float* __restrict__ bip,
    const float* __restrict__ bcp, const float* __restrict__ bop,
    float* __restrict__ hout, float* __restrict__ cout)
{
  extern __shared__ __align__(16) char smem[];
  const int tid  = threadIdx.x;
  const int w    = tid >> 6;
  const int g    = w & 3;              // gate
  const int nh   = w >> 2;             // n-half (0/1)
  const int lane = tid & 63;
  const int la   = lane & 31;
  const int hh   = lane >> 5;

  int bid = blockIdx.x;
  int wg  = (bid & 7) * 512 + (bid >> 3);      // XCD-bijective (4096 = 8*512)
  const int m0 = (wg >> 2) * 64;
  const int nt = wg & 3;
  const int n0 = nt * 64;

  const short* Bbase = Wt + (size_t)(g * 8 + nt * 2 + nh) * 16384;

  f32x16 acc[2] = {};                  // 2 m-frags of 32x32 = 32 AGPR
  bf16x8 bB[4][2];                     // 4-deep B ring = 32 VGPR

  auto loadB = [&](int c) {
    const short* p = Bbase + c * 1024 + lane * 8;
    bB[c & 3][0] = *(const bf16x8*)(p);
    bB[c & 3][1] = *(const bf16x8*)(p + 512);
  };

  // ---- stage full A-tile (64 rows x 512 k) as bf16 fragments, once ----
  // source-linear: wave reads 1KB contiguous per iter; LDS writes XOR-swizzled.
#pragma unroll
  for (int i = 0; i < 16; ++i) {
    const int idx  = tid + 512 * i;            // float4 index over 64x128
    const int row  = idx >> 7;
    const int k4   = idx & 127;
    const float* src = (k4 < 64)
        ? (x     + (size_t)(m0 + row) * 256 + k4 * 4)
        : (hprev + (size_t)(m0 + row) * 256 + (k4 - 64) * 4);
    float4 v = *(const float4*)src;
    const int c   = k4 >> 3, ks = (k4 >> 2) & 1, hi2 = (k4 >> 1) & 1;
    const int e4  = (k4 & 1) * 4;
    const int mh  = row >> 5, r31 = row & 31;
    const int swz = (((c << 1) | ks) & 7) << 4;
    const int byte = ((c * 2 + mh) * 2 + ks) * 1024
                   + ((hi2 * 512 + r31 * 16) ^ swz) + e4 * 2;
    uint2 u; u.x = pk2(v.x, v.y); u.y = pk2(v.z, v.w);
    *(uint2*)(smem + byte) = u;
  }
  // B(0..3) issued after A-writes (A vmem fully retired by the writes above)
  loadB(0); loadB(1); loadB(2); loadB(3);
  BAR();                               // A-tile visible to all 8 waves

  // ---- barrier-free K loop, fully unrolled (static ring indices) ----
#pragma unroll
  for (int c = 0; c < NCH; ++c) {
    if      (c <  NCH - 3) { WAITV(6); }       // B(c) done, 3 chunks in flight
    else if (c == NCH - 3) { WAITV(4); }
    else if (c == NCH - 2) { WAITV(2); }
    else                   { WAITV(0); }
#pragma unroll
    for (int ks = 0; ks < 2; ++ks) {
      const int swz = (((c << 1) | ks) & 7) << 4;
      const int b0  = ((c * 2 + 0) * 2 + ks) * 1024 + ((lane * 16) ^ swz);
      const int b1  = ((c * 2 + 1) * 2 + ks) * 1024 + ((lane * 16) ^ swz);
      bf16x8 a0 = *(const bf16x8*)(smem + b0);
      bf16x8 a1 = *(const bf16x8*)(smem + b1);
      acc[0] = __builtin_amdgcn_mfma_f32_32x32x16_bf16(a0, bB[c & 3][ks], acc[0], 0, 0, 0);
      acc[1] = __builtin_amdgcn_mfma_f32_32x32x16_bf16(a1, bB[c & 3][ks], acc[1], 0, 0, 0);
    }
    if (c + 4 < NCH) loadB(c + 4);     // refill slot (c+4)&3 == c&3 (just read)
  }

  // ---- epilogue: G-exchange in LDS (reuses A region after barrier) ----
  const int ccol = tid & 63;
  const int rs   = tid >> 6;           // 8 segs x 8 rows
  const size_t gb = (size_t)(m0 + rs * 8) * 256 + n0 + ccol;
  BAR();                               // all A reads done; smem becomes G

  float cp[8];
#pragma unroll
  for (int j = 0; j < 8; ++j) cp[j] = cprev[gb + (size_t)j * 256];

  const float* bptr = (g == 0) ? bfp : (g == 1) ? bip : (g == 2) ? bcp : bop;
  const float bias = bptr[n0 + nh * 32 + la];
  short* G = (short*)smem;             // [g][col 64][ROWP]
#pragma unroll
  for (int mi = 0; mi < 2; ++mi) {
    const int col = nh * 32 + la;
#pragma unroll
    for (int rq = 0; rq < 4; ++rq) {
      const int row0 = rq * 8 + 4 * hh + mi * 32;
      float t[4];
#pragma unroll
      for (int e = 0; e < 4; ++e) {
        float vv = acc[mi][rq * 4 + e] + bias;
        t[e] = (g == 2) ? fast_tanh(vv) : fast_sigmoid(vv);
      }
      uint2 u; u.x = pk2(t[0], t[1]); u.y = pk2(t[2], t[3]);
      *(uint2*)(G + (g * 64 + col) * ROWP + row0) = u;
    }
  }
  BAR();

  // ---- combine + store: thread -> col = tid&63, rows rs*8..+7 ----
  {
    const short* Gp = G + ccol * ROWP + rs * 8;
    bf16x8 gf[4];
#pragma unroll
    for (int t = 0; t < 4; ++t) gf[t] = *(const bf16x8*)(Gp + t * 64 * ROWP);
#pragma unroll
    for (int j = 0; j < 8; ++j) {
      float fg = bf2f(gf[0][j]);
      float ig = bf2f(gf[1][j]);
      float cg = bf2f(gf[2][j]);
      float og = bf2f(gf[3][j]);
      float cnew = fg * cp[j] + ig * cg;
      float hnew = og * fast_tanh(cnew);
      hout[gb + (size_t)j * 256] = hnew;
      cout[gb + (size_t)j * 256] = cnew;
    }
  }
}

extern "C" void kernel_launch(void* const* d_in, const int* in_sizes, int n_in,
                              void* d_out, int out_size, void* d_ws, size_t ws_size,
                              hipStream_t stream) {
  const float* x     = (const float*)d_in[0];
  const float* hprev = (const float*)d_in[1];
  const float* cprev = (const float*)d_in[2];
  const float* Wf    = (const float*)d_in[3];
  const float* Wi    = (const float*)d_in[4];
  const float* Wc    = (const float*)d_in[5];
  const float* Wo    = (const float*)d_in[6];
  const float* bfp   = (const float*)d_in[7];
  const float* bip   = (const float*)d_in[8];
  const float* bcp   = (const float*)d_in[9];
  const float* bop   = (const float*)d_in[10];
  float* out = (float*)d_out;
  short* Wt  = (short*)d_ws;     // 1 MB scratch

  cvt_weights<<<2048, 256, 0, stream>>>(Wf, Wi, Wc, Wo, Wt);

  lstm_fused<<<dim3(4096), dim3(512), SMEM_BYTES, stream>>>(
      x, hprev, cprev, Wt, bfp, bip, bcp, bop,
      out, out + (size_t)BATCH * UNITS);
}